// Round 3
// baseline (3365.593 us; speedup 1.0000x reference)
//
#include <hip/hip_runtime.h>

// Problem constants (B=2, S=1024, D=1024, H=16, hd=64, L=4, M=12)
// All external tensors are float32 (per reference). Workspace intermediates bf16.
#define BATCH 2
#define SEQ   1024
#define DIM   1024
#define NH    16
#define HD    64
#define NL    4
#define NM    12   // 3*NL
#define NTOK  (BATCH*SEQ)          // 2048
#define MEMROWS (BATCH*SEQ*NM)     // 24576
#define OUTT  2097152              // elements per output tensor
#define NEGBIG (-1.0e30f)

__device__ __forceinline__ float bf2f(ushort u) {
    union { unsigned int i; float f; } t; t.i = ((unsigned int)u) << 16; return t.f;
}
__device__ __forceinline__ ushort f2bf(float f) {
    union { float f; unsigned int i; } t; t.f = f;
    unsigned int i = t.i;
    unsigned int lsb = (i >> 16) & 1u;
    i += 0x7fffu + lsb;           // round-to-nearest-even
    return (ushort)(i >> 16);
}

// dtype-generic 4-element loads / 1-element store
__device__ __forceinline__ void ld4(const float* p, float* o) {
    float4 v = *(const float4*)p; o[0] = v.x; o[1] = v.y; o[2] = v.z; o[3] = v.w;
}
__device__ __forceinline__ void ld4(const ushort* p, float* o) {
    ushort4 v = *(const ushort4*)p;
    o[0] = bf2f(v.x); o[1] = bf2f(v.y); o[2] = bf2f(v.z); o[3] = bf2f(v.w);
}
__device__ __forceinline__ void st1(float* p, float v)  { *p = v; }
__device__ __forceinline__ void st1(ushort* p, float v) { *p = f2bf(v); }

// ---------------------------------------------------------------------------
// Generic GEMM: C[M,N] = A[M,K] @ W[N,K]^T + bias[N], fp32 accumulate.
// A: fp32 or bf16; W,bias: fp32; C: fp32 or bf16. Tile 64x64, BK=16.
// ---------------------------------------------------------------------------
#define BM 64
#define BN 64
#define BKK 16
template <typename TA, typename TC>
__global__ __launch_bounds__(256) void gemm_bt(
    const TA* __restrict__ A, const float* __restrict__ W,
    const float* __restrict__ bias, TC* __restrict__ C,
    int N, int K)
{
    __shared__ float As[BKK][BM + 1];
    __shared__ float Bs[BKK][BN + 1];
    const int tid = threadIdx.x;
    const int tx = tid & 15, ty = tid >> 4;
    const int row0 = blockIdx.y * BM;
    const int col0 = blockIdx.x * BN;
    const int lr = tid >> 2;            // 0..63 tile row to load
    const int lc = (tid & 3) << 2;      // k-offset 0,4,8,12

    float acc[4][4] = {};

    for (int k0 = 0; k0 < K; k0 += BKK) {
        float av[4], bv[4];
        ld4(A + (size_t)(row0 + lr) * K + k0 + lc, av);
        ld4(W + (size_t)(col0 + lr) * K + k0 + lc, bv);
#pragma unroll
        for (int i = 0; i < 4; i++) { As[lc + i][lr] = av[i]; Bs[lc + i][lr] = bv[i]; }
        __syncthreads();
#pragma unroll
        for (int kk = 0; kk < BKK; kk++) {
            float a[4], b[4];
#pragma unroll
            for (int i = 0; i < 4; i++) a[i] = As[kk][ty * 4 + i];
#pragma unroll
            for (int j = 0; j < 4; j++) b[j] = Bs[kk][tx * 4 + j];
#pragma unroll
            for (int i = 0; i < 4; i++)
#pragma unroll
                for (int j = 0; j < 4; j++)
                    acc[i][j] = fmaf(a[i], b[j], acc[i][j]);
        }
        __syncthreads();
    }
#pragma unroll
    for (int i = 0; i < 4; i++) {
        int r = row0 + ty * 4 + i;
#pragma unroll
        for (int j = 0; j < 4; j++) {
            int c = col0 + tx * 4 + j;
            st1(C + (size_t)r * N + c, acc[i][j] + bias[c]);
        }
    }
}

// ---------------------------------------------------------------------------
// QKV GEMM, scattered epilogue into d_out (fp32):
// q -> out[3*OUTT..], k -> out[OUTT..], v -> out[2*OUTT..], layout (B,H,S,hd)
// ---------------------------------------------------------------------------
__global__ __launch_bounds__(256) void gemm_qkv_kernel(
    const float* __restrict__ A, const float* __restrict__ W,
    const float* __restrict__ bias, float* __restrict__ out)
{
    __shared__ float As[BKK][BM + 1];
    __shared__ float Bs[BKK][BN + 1];
    const int tid = threadIdx.x;
    const int tx = tid & 15, ty = tid >> 4;
    const int row0 = blockIdx.y * BM;
    const int col0 = blockIdx.x * BN;
    const int lr = tid >> 2;
    const int lc = (tid & 3) << 2;
    const int K = DIM;

    float acc[4][4] = {};

    for (int k0 = 0; k0 < K; k0 += BKK) {
        float av[4], bv[4];
        ld4(A + (size_t)(row0 + lr) * K + k0 + lc, av);
        ld4(W + (size_t)(col0 + lr) * K + k0 + lc, bv);
#pragma unroll
        for (int i = 0; i < 4; i++) { As[lc + i][lr] = av[i]; Bs[lc + i][lr] = bv[i]; }
        __syncthreads();
#pragma unroll
        for (int kk = 0; kk < BKK; kk++) {
            float a[4], b[4];
#pragma unroll
            for (int i = 0; i < 4; i++) a[i] = As[kk][ty * 4 + i];
#pragma unroll
            for (int j = 0; j < 4; j++) b[j] = Bs[kk][tx * 4 + j];
#pragma unroll
            for (int i = 0; i < 4; i++)
#pragma unroll
                for (int j = 0; j < 4; j++)
                    acc[i][j] = fmaf(a[i], b[j], acc[i][j]);
        }
        __syncthreads();
    }
#pragma unroll
    for (int i = 0; i < 4; i++) {
        int r = row0 + ty * 4 + i;          // token row: b*SEQ + s
        int b = r >> 10, s = r & (SEQ - 1);
#pragma unroll
        for (int j = 0; j < 4; j++) {
            int c = col0 + tx * 4 + j;      // 0..3071
            int t = c >> 10;                // 0=q,1=k,2=v
            int h = (c >> 6) & 15;
            int d = c & 63;
            size_t base = (t == 0) ? (size_t)(3 * OUTT)
                        : (t == 1) ? (size_t)(OUTT) : (size_t)(2 * OUTT);
            out[base + (((size_t)(b * NH + h) * SEQ + s) * HD) + d] = acc[i][j] + bias[c];
        }
    }
}

// ---------------------------------------------------------------------------
// LayerNorm of mem rows (fp32 in, bf16 out). mem[b,s,c*4+l, h*64+d] = past_c[l,b,h,s,d]
// ---------------------------------------------------------------------------
__global__ __launch_bounds__(256) void ln_mem_kernel(
    const float* __restrict__ pq, const float* __restrict__ pk,
    const float* __restrict__ pv, ushort* __restrict__ mem_n)
{
    const int r = blockIdx.x;
    const int idx = r % NM;
    const int bs = r / NM;
    const int s = bs & (SEQ - 1);
    const int b = bs >> 10;
    const int c = idx >> 2;
    const int l = idx & 3;
    const float* src = (c == 0) ? pq : ((c == 1) ? pk : pv);
    const int tid = threadIdx.x;

    float vals[4];
    float sum = 0.f, sumsq = 0.f;
#pragma unroll
    for (int i = 0; i < 4; i++) {
        int dp = i * 256 + tid;
        int h = dp >> 6, d = dp & 63;
        float v = src[((((size_t)(l * BATCH + b) * NH + h) * SEQ + s) * HD) + d];
        vals[i] = v; sum += v; sumsq += v * v;
    }
    __shared__ float rs[256], rq[256];
    rs[tid] = sum; rq[tid] = sumsq;
    __syncthreads();
    for (int st = 128; st > 0; st >>= 1) {
        if (tid < st) { rs[tid] += rs[tid + st]; rq[tid] += rq[tid + st]; }
        __syncthreads();
    }
    float mu  = rs[0] * (1.f / 1024.f);
    float var = rq[0] * (1.f / 1024.f) - mu * mu;
    var = fmaxf(var, 0.f);
    float inv = rsqrtf(var + 1e-5f);
    ushort* dst = mem_n + (size_t)r * 1024;
#pragma unroll
    for (int i = 0; i < 4; i++) {
        int dp = i * 256 + tid;
        dst[dp] = f2bf((vals[i] - mu) * inv);
    }
}

// ---------------------------------------------------------------------------
// Fused attention per (b,h,s). q,k,v fp32 from d_out regions, rkv bf16 ws.
// Finite mask, LDS tree reductions. merged (2048x1024) fp32.
// ---------------------------------------------------------------------------
__global__ __launch_bounds__(256) void attn_kernel(
    const float* __restrict__ out_qkv, const ushort* __restrict__ rkv,
    float* __restrict__ merged)
{
    const int blk = blockIdx.x;          // ((b*NH + h) * SEQ + s)
    const int s = blk & (SEQ - 1);
    const int bh = blk >> 10;
    const int h = bh & 15;
    const int b = bh >> 4;
    const int tid = threadIdx.x;

    __shared__ float qv[64];
    __shared__ float w[SEQ + NM];
    __shared__ float red[256];
    __shared__ float part[4][64];

    const float* qbase = out_qkv + (size_t)3 * OUTT + ((size_t)bh * SEQ + s) * HD;
    const float* kbase = out_qkv + (size_t)OUTT     + ((size_t)bh * SEQ) * HD;
    const float* vbase = out_qkv + (size_t)2 * OUTT + ((size_t)bh * SEQ) * HD;

    if (tid < 64) qv[tid] = qbase[tid];
    __syncthreads();

    // token scores (causal, finite mask)
    for (int j = tid; j < SEQ; j += 256) {
        float sc = NEGBIG;
        if (j <= s) {
            const float* krow = kbase + (size_t)j * HD;
            float sum = 0.f;
#pragma unroll
            for (int d = 0; d < HD; d += 4) {
                float4 k4 = *(const float4*)(krow + d);
                sum += qv[d + 0] * k4.x + qv[d + 1] * k4.y
                     + qv[d + 2] * k4.z + qv[d + 3] * k4.w;
            }
            sc = sum * 0.125f;
        }
        w[j] = sc;
    }
    // mem scores
    if (tid < NM) {
        const ushort* rrow = rkv + ((size_t)(b * SEQ + s) * NM + tid) * 2048 + h * HD;
        float sum = 0.f;
#pragma unroll
        for (int d = 0; d < HD; d += 4) {
            ushort4 k4 = *(const ushort4*)(rrow + d);
            sum += qv[d + 0] * bf2f(k4.x) + qv[d + 1] * bf2f(k4.y)
                 + qv[d + 2] * bf2f(k4.z) + qv[d + 3] * bf2f(k4.w);
        }
        w[SEQ + tid] = sum * 0.125f;
    }
    __syncthreads();

    // softmax max (LDS tree)
    float m = NEGBIG;
    for (int j = tid; j < SEQ + NM; j += 256) m = fmaxf(m, w[j]);
    red[tid] = m;
    __syncthreads();
    for (int st = 128; st > 0; st >>= 1) {
        if (tid < st) red[tid] = fmaxf(red[tid], red[tid + st]);
        __syncthreads();
    }
    m = red[0];
    __syncthreads();

    // exp + sum
    float ssum = 0.f;
    for (int j = tid; j < SEQ + NM; j += 256) {
        float e = __expf(w[j] - m);
        w[j] = e;
        ssum += e;
    }
    red[tid] = ssum;
    __syncthreads();
    for (int st = 128; st > 0; st >>= 1) {
        if (tid < st) red[tid] += red[tid + st];
        __syncthreads();
    }
    const float inv = 1.0f / red[0];

    // context
    const int d = tid & 63;
    const int g = tid >> 6;
    float acc = 0.f;
    for (int j = g; j <= s; j += 4) {
        acc += w[j] * vbase[(size_t)j * HD + d];
    }
    for (int mm = g; mm < NM; mm += 4) {
        acc += w[SEQ + mm] * bf2f(rkv[((size_t)(b * SEQ + s) * NM + mm) * 2048 + 1024 + h * HD + d]);
    }
    part[g][d] = acc;
    __syncthreads();
    if (tid < 64) {
        float r2 = (part[0][tid] + part[1][tid] + part[2][tid] + part[3][tid]) * inv;
        merged[(size_t)(b * SEQ + s) * 1024 + h * HD + tid] = r2;
    }
}

// ---------------------------------------------------------------------------
extern "C" void kernel_launch(void* const* d_in, const int* in_sizes, int n_in,
                              void* d_out, int out_size, void* d_ws, size_t ws_size,
                              hipStream_t stream) {
    const float* x    = (const float*)d_in[0];
    const float* pk   = (const float*)d_in[1];
    const float* pv   = (const float*)d_in[2];
    const float* pq   = (const float*)d_in[3];
    const float* Wqkv = (const float*)d_in[4];
    const float* bqkv = (const float*)d_in[5];
    const float* Wout = (const float*)d_in[6];
    const float* bout = (const float*)d_in[7];
    float* out = (float*)d_out;

    // ws layout (bytes): mem_n bf16 50.3MB | rkv bf16 100.7MB ; merged fp32
    // aliases mem_n region (dead after rkv GEMM). Total ~151 MB.
    ushort* mem_n  = (ushort*)d_ws;                       // 24576*1024 bf16
    ushort* rkv    = mem_n + (size_t)MEMROWS * 1024;      // 24576*2048 bf16
    float*  merged = (float*)d_ws;                        // 2048*1024 fp32 (alias)

    // 1. q,k,v = x @ Wqkv^T + bqkv -> d_out regions (fp32)
    gemm_qkv_kernel<<<dim3(3072 / BN, NTOK / BM), 256, 0, stream>>>(x, Wqkv, bqkv, out);
    // 2. layernorm of mem rows -> bf16
    ln_mem_kernel<<<MEMROWS, 256, 0, stream>>>(pq, pk, pv, mem_n);
    // 3. rkv = mem_n @ Wqkv[D:3D]^T + bqkv[D:3D] -> bf16
    gemm_bt<ushort, ushort><<<dim3(2048 / BN, MEMROWS / BM), 256, 0, stream>>>(
        mem_n, Wqkv + (size_t)1024 * 1024, bqkv + 1024, rkv, 2048, 1024);
    // 4. fused attention -> merged fp32 (aliases mem_n; mem_n no longer read)
    attn_kernel<<<BATCH * NH * SEQ, 256, 0, stream>>>(out, rkv, merged);
    // 5. out = merged @ Wout^T + bout (fp32)
    gemm_bt<float, float><<<dim3(1024 / BN, NTOK / BM), 256, 0, stream>>>(
        merged, Wout, bout, out, 1024, 1024);
}

// Round 4
// 1711.745 us; speedup vs baseline: 1.9662x; 1.9662x over previous
//
#include <hip/hip_runtime.h>

// Problem constants (B=2, S=1024, D=1024, H=16, hd=64, L=4, M=12)
// External tensors fp32. Workspace intermediates bf16/fp32.
#define BATCH 2
#define SEQ   1024
#define DIM   1024
#define NH    16
#define HD    64
#define NL    4
#define NM    12   // 3*NL
#define NTOK  (BATCH*SEQ)          // 2048
#define MEMROWS (BATCH*SEQ*NM)     // 24576
#define OUTT  2097152              // elements per output tensor
#define NEGBIG (-1.0e30f)

__device__ __forceinline__ float bf2f(ushort u) {
    union { unsigned int i; float f; } t; t.i = ((unsigned int)u) << 16; return t.f;
}
__device__ __forceinline__ ushort f2bf(float f) {
    union { float f; unsigned int i; } t; t.f = f;
    unsigned int i = t.i;
    unsigned int lsb = (i >> 16) & 1u;
    i += 0x7fffu + lsb;
    return (ushort)(i >> 16);
}
__device__ __forceinline__ void ld4(const float* p, float* o) {
    float4 v = *(const float4*)p; o[0] = v.x; o[1] = v.y; o[2] = v.z; o[3] = v.w;
}
__device__ __forceinline__ void ld4(const ushort* p, float* o) {
    ushort4 v = *(const ushort4*)p;
    o[0] = bf2f(v.x); o[1] = bf2f(v.y); o[2] = bf2f(v.z); o[3] = bf2f(v.w);
}
__device__ __forceinline__ void st1(float* p, float v)  { *p = v; }
__device__ __forceinline__ void st1(ushort* p, float v) { *p = f2bf(v); }

#define BM 64
#define BN 64
#define BKK 16

// ---------------------------------------------------------------------------
// Generic GEMM: C[M,N] = A[M,K] @ W[N,K]^T + bias[N], fp32 accumulate.
// ---------------------------------------------------------------------------
template <typename TA, typename TC>
__global__ __launch_bounds__(256) void gemm_bt(
    const TA* __restrict__ A, const float* __restrict__ W,
    const float* __restrict__ bias, TC* __restrict__ C,
    int N, int K)
{
    __shared__ float As[BKK][BM + 1];
    __shared__ float Bs[BKK][BN + 1];
    const int tid = threadIdx.x;
    const int tx = tid & 15, ty = tid >> 4;
    const int row0 = blockIdx.y * BM;
    const int col0 = blockIdx.x * BN;
    const int lr = tid >> 2;
    const int lc = (tid & 3) << 2;

    float acc[4][4] = {};
    for (int k0 = 0; k0 < K; k0 += BKK) {
        float av[4], bv[4];
        ld4(A + (size_t)(row0 + lr) * K + k0 + lc, av);
        ld4(W + (size_t)(col0 + lr) * K + k0 + lc, bv);
#pragma unroll
        for (int i = 0; i < 4; i++) { As[lc + i][lr] = av[i]; Bs[lc + i][lr] = bv[i]; }
        __syncthreads();
#pragma unroll
        for (int kk = 0; kk < BKK; kk++) {
            float a[4], b[4];
#pragma unroll
            for (int i = 0; i < 4; i++) a[i] = As[kk][ty * 4 + i];
#pragma unroll
            for (int j = 0; j < 4; j++) b[j] = Bs[kk][tx * 4 + j];
#pragma unroll
            for (int i = 0; i < 4; i++)
#pragma unroll
                for (int j = 0; j < 4; j++)
                    acc[i][j] = fmaf(a[i], b[j], acc[i][j]);
        }
        __syncthreads();
    }
#pragma unroll
    for (int i = 0; i < 4; i++) {
        int r = row0 + ty * 4 + i;
#pragma unroll
        for (int j = 0; j < 4; j++) {
            int c = col0 + tx * 4 + j;
            st1(C + (size_t)r * N + c, acc[i][j] + bias[c]);
        }
    }
}

// ---------------------------------------------------------------------------
// QKV GEMM, scattered epilogue into d_out (fp32): q->3*OUTT, k->OUTT, v->2*OUTT
// ---------------------------------------------------------------------------
__global__ __launch_bounds__(256) void gemm_qkv_kernel(
    const float* __restrict__ A, const float* __restrict__ W,
    const float* __restrict__ bias, float* __restrict__ out)
{
    __shared__ float As[BKK][BM + 1];
    __shared__ float Bs[BKK][BN + 1];
    const int tid = threadIdx.x;
    const int tx = tid & 15, ty = tid >> 4;
    const int row0 = blockIdx.y * BM;
    const int col0 = blockIdx.x * BN;
    const int lr = tid >> 2;
    const int lc = (tid & 3) << 2;

    float acc[4][4] = {};
    for (int k0 = 0; k0 < DIM; k0 += BKK) {
        float av[4], bv[4];
        ld4(A + (size_t)(row0 + lr) * DIM + k0 + lc, av);
        ld4(W + (size_t)(col0 + lr) * DIM + k0 + lc, bv);
#pragma unroll
        for (int i = 0; i < 4; i++) { As[lc + i][lr] = av[i]; Bs[lc + i][lr] = bv[i]; }
        __syncthreads();
#pragma unroll
        for (int kk = 0; kk < BKK; kk++) {
            float a[4], b[4];
#pragma unroll
            for (int i = 0; i < 4; i++) a[i] = As[kk][ty * 4 + i];
#pragma unroll
            for (int j = 0; j < 4; j++) b[j] = Bs[kk][tx * 4 + j];
#pragma unroll
            for (int i = 0; i < 4; i++)
#pragma unroll
                for (int j = 0; j < 4; j++)
                    acc[i][j] = fmaf(a[i], b[j], acc[i][j]);
        }
        __syncthreads();
    }
#pragma unroll
    for (int i = 0; i < 4; i++) {
        int r = row0 + ty * 4 + i;
        int b = r >> 10, s = r & (SEQ - 1);
#pragma unroll
        for (int j = 0; j < 4; j++) {
            int c = col0 + tx * 4 + j;
            int t = c >> 10;                // 0=q,1=k,2=v
            int h = (c >> 6) & 15;
            int d = c & 63;
            size_t base = (t == 0) ? (size_t)(3 * OUTT)
                        : (t == 1) ? (size_t)(OUTT) : (size_t)(2 * OUTT);
            out[base + (((size_t)(b * NH + h) * SEQ + s) * HD) + d] = acc[i][j] + bias[c];
        }
    }
}

// ---------------------------------------------------------------------------
// LayerNorm of mem rows (fp32 in, bf16 out)
// ---------------------------------------------------------------------------
__global__ __launch_bounds__(256) void ln_mem_kernel(
    const float* __restrict__ pq, const float* __restrict__ pk,
    const float* __restrict__ pv, ushort* __restrict__ mem_n)
{
    const int r = blockIdx.x;
    const int idx = r % NM;
    const int bs = r / NM;
    const int s = bs & (SEQ - 1);
    const int b = bs >> 10;
    const int c = idx >> 2;
    const int l = idx & 3;
    const float* src = (c == 0) ? pq : ((c == 1) ? pk : pv);
    const int tid = threadIdx.x;

    float vals[4];
    float sum = 0.f, sumsq = 0.f;
#pragma unroll
    for (int i = 0; i < 4; i++) {
        int dp = i * 256 + tid;
        int h = dp >> 6, d = dp & 63;
        float v = src[((((size_t)(l * BATCH + b) * NH + h) * SEQ + s) * HD) + d];
        vals[i] = v; sum += v; sumsq += v * v;
    }
    __shared__ float rs[256], rq[256];
    rs[tid] = sum; rq[tid] = sumsq;
    __syncthreads();
    for (int st = 128; st > 0; st >>= 1) {
        if (tid < st) { rs[tid] += rs[tid + st]; rq[tid] += rq[tid + st]; }
        __syncthreads();
    }
    float mu  = rs[0] * (1.f / 1024.f);
    float var = fmaxf(rq[0] * (1.f / 1024.f) - mu * mu, 0.f);
    float inv = rsqrtf(var + 1e-5f);
    ushort* dst = mem_n + (size_t)r * 1024;
#pragma unroll
    for (int i = 0; i < 4; i++) {
        int dp = i * 256 + tid;
        dst[dp] = f2bf((vals[i] - mu) * inv);
    }
}

// ---------------------------------------------------------------------------
// qproj[b,s,h,:] = q[b,h,s,:] @ Wk_h  (per-head GEMM: M=2048, N=1024, K=64)
// q read from d_out (fp32, B,H,S,hd). Output bf16 [(bs)*16 + h][1024].
// ---------------------------------------------------------------------------
__global__ __launch_bounds__(256) void qproj_kernel(
    const float* __restrict__ out_qkv, const float* __restrict__ Wk,
    ushort* __restrict__ qproj)
{
    __shared__ float As[BKK][BM + 1];
    __shared__ float Bs[BKK][BN + 1];
    const int tid = threadIdx.x;
    const int tx = tid & 15, ty = tid >> 4;
    const int row0 = blockIdx.y * BM;
    const int col0 = blockIdx.x * BN;
    const int h = blockIdx.z;
    const int lr = tid >> 2;            // A-load row
    const int lc = (tid & 3) << 2;      // A-load k offset
    const int bkk = tid >> 4;           // B-load k row (0..15)
    const int bc4 = (tid & 15) << 2;    // B-load col offset

    const float* qbase = out_qkv + (size_t)3 * OUTT;

    float acc[4][4] = {};
    for (int k0 = 0; k0 < HD; k0 += BKK) {
        int row = row0 + lr;
        int b = row >> 10, s = row & (SEQ - 1);
        float av[4], bv[4];
        ld4(qbase + (((size_t)(b * NH + h) * SEQ + s) * HD) + k0 + lc, av);
        ld4(Wk + (size_t)(h * HD + k0 + bkk) * DIM + col0 + bc4, bv);
#pragma unroll
        for (int i = 0; i < 4; i++) As[lc + i][lr] = av[i];
#pragma unroll
        for (int i = 0; i < 4; i++) Bs[bkk][bc4 + i] = bv[i];
        __syncthreads();
#pragma unroll
        for (int kk = 0; kk < BKK; kk++) {
            float a[4], b2[4];
#pragma unroll
            for (int i = 0; i < 4; i++) a[i] = As[kk][ty * 4 + i];
#pragma unroll
            for (int j = 0; j < 4; j++) b2[j] = Bs[kk][tx * 4 + j];
#pragma unroll
            for (int i = 0; i < 4; i++)
#pragma unroll
                for (int j = 0; j < 4; j++)
                    acc[i][j] = fmaf(a[i], b2[j], acc[i][j]);
        }
        __syncthreads();
    }
#pragma unroll
    for (int i = 0; i < 4; i++) {
        int r = row0 + ty * 4 + i;
#pragma unroll
        for (int j = 0; j < 4; j++) {
            int c = col0 + tx * 4 + j;
            qproj[((size_t)r * NH + h) * DIM + c] = f2bf(acc[i][j]);
        }
    }
}

// ---------------------------------------------------------------------------
// mem_scores[(bs*16+h)*12+m] = 0.125*( mem_n[bs,m,:]·qproj[bs,h,:] + q_h·bk_h )
// block per bs (2048), 256 threads. 192 threads do the 16x12 dots from LDS.
// ---------------------------------------------------------------------------
__global__ __launch_bounds__(256) void mem_scores_kernel(
    const ushort* __restrict__ mem_n, const ushort* __restrict__ qproj,
    const float* __restrict__ out_qkv, const float* __restrict__ bqkv,
    float* __restrict__ msc)
{
    __shared__ ushort memL[NM][1032];
    __shared__ ushort qpL[NH][1032];
    __shared__ float scL[192];
    __shared__ float qbPart[NH][4];
    const int bs = blockIdx.x;
    const int tid = threadIdx.x;

    for (int t = tid; t < NM * 256; t += 256) {
        int m = t >> 8, c4 = (t & 255) << 2;
        *(ushort4*)&memL[m][c4] = *(const ushort4*)(mem_n + ((size_t)bs * NM + m) * 1024 + c4);
    }
    for (int t = tid; t < NH * 256; t += 256) {
        int h = t >> 8, c4 = (t & 255) << 2;
        *(ushort4*)&qpL[h][c4] = *(const ushort4*)(qproj + ((size_t)bs * NH + h) * 1024 + c4);
    }
    // qbk partials: 64 threads, each (h, quarter): sum over 16 d's
    if (tid >= 192) {
        int t2 = tid - 192;
        int h = t2 >> 2, ch = t2 & 3;
        int b = bs >> 10, s = bs & (SEQ - 1);
        const float* qrow = out_qkv + (size_t)3 * OUTT + ((size_t)(b * NH + h) * SEQ + s) * HD;
        float qb = 0.f;
#pragma unroll
        for (int d = 0; d < 16; d++)
            qb += qrow[ch * 16 + d] * bqkv[DIM + h * HD + ch * 16 + d];
        qbPart[h][ch] = qb;
    }
    __syncthreads();

    if (tid < 192) {
        int h = tid / NM, m = tid % NM;
        float acc = 0.f;
#pragma unroll 4
        for (int c = 0; c < 1024; c++)
            acc = fmaf(bf2f(memL[m][c]), bf2f(qpL[h][c]), acc);
        float qbk = qbPart[h][0] + qbPart[h][1] + qbPart[h][2] + qbPart[h][3];
        msc[((size_t)bs * NH + h) * NM + m] = 0.125f * (acc + qbk);
    }
}

// ---------------------------------------------------------------------------
// Attention per (b,h,s): token scores (causal) + precomputed mem scores,
// softmax, token context -> merged (fp32). Emits normalized mem weights
// wmem[(bs*16+h)*16 + m] (m=0..11) and their sum at m=12.
// ---------------------------------------------------------------------------
__global__ __launch_bounds__(256) void attn_kernel(
    const float* __restrict__ out_qkv, const float* __restrict__ msc,
    float* __restrict__ merged, float* __restrict__ wmem)
{
    const int blk = blockIdx.x;          // (b*16 + h)*1024 + s
    const int s = blk & (SEQ - 1);
    const int bh = blk >> 10;
    const int h = bh & 15;
    const int b = bh >> 4;
    const int bs = b * SEQ + s;
    const int tid = threadIdx.x;

    __shared__ float qv[64];
    __shared__ float w[SEQ + NM];
    __shared__ float red[256];
    __shared__ float part[4][64];

    const float* qbase = out_qkv + (size_t)3 * OUTT + ((size_t)bh * SEQ + s) * HD;
    const float* kbase = out_qkv + (size_t)OUTT     + ((size_t)bh * SEQ) * HD;
    const float* vbase = out_qkv + (size_t)2 * OUTT + ((size_t)bh * SEQ) * HD;

    if (tid < 64) qv[tid] = qbase[tid];
    __syncthreads();

    for (int j = tid; j < SEQ; j += 256) {
        float sc = NEGBIG;
        if (j <= s) {
            const float* krow = kbase + (size_t)j * HD;
            float sum = 0.f;
#pragma unroll
            for (int d = 0; d < HD; d += 4) {
                float4 k4 = *(const float4*)(krow + d);
                sum += qv[d + 0] * k4.x + qv[d + 1] * k4.y
                     + qv[d + 2] * k4.z + qv[d + 3] * k4.w;
            }
            sc = sum * 0.125f;
        }
        w[j] = sc;
    }
    if (tid < NM) w[SEQ + tid] = msc[((size_t)bs * NH + h) * NM + tid];
    __syncthreads();

    float m = NEGBIG;
    for (int j = tid; j < SEQ + NM; j += 256) m = fmaxf(m, w[j]);
    red[tid] = m;
    __syncthreads();
    for (int st = 128; st > 0; st >>= 1) {
        if (tid < st) red[tid] = fmaxf(red[tid], red[tid + st]);
        __syncthreads();
    }
    m = red[0];
    __syncthreads();

    float ssum = 0.f;
    for (int j = tid; j < SEQ + NM; j += 256) {
        float e = __expf(w[j] - m);
        w[j] = e;
        ssum += e;
    }
    red[tid] = ssum;
    __syncthreads();
    for (int st = 128; st > 0; st >>= 1) {
        if (tid < st) red[tid] += red[tid + st];
        __syncthreads();
    }
    const float inv = 1.0f / red[0];

    // normalized mem weights + sum
    size_t wb = ((size_t)bs * NH + h) * 16;
    if (tid < NM) wmem[wb + tid] = w[SEQ + tid] * inv;
    if (tid == 0) {
        float ws = 0.f;
#pragma unroll
        for (int mm = 0; mm < NM; mm++) ws += w[SEQ + mm];
        wmem[wb + 12] = ws * inv;
    }

    // token context
    const int d = tid & 63;
    const int g = tid >> 6;
    float acc = 0.f;
    for (int j = g; j <= s; j += 4)
        acc += w[j] * vbase[(size_t)j * HD + d];
    part[g][d] = acc;
    __syncthreads();
    if (tid < 64) {
        float r2 = (part[0][tid] + part[1][tid] + part[2][tid] + part[3][tid]) * inv;
        merged[(size_t)bs * DIM + h * HD + tid] = r2;
    }
}

// ---------------------------------------------------------------------------
// wvec[bs,h,:] = sum_m wmem[bs,h,m] * mem_n[bs,m,:]  (bf16 out)
// ---------------------------------------------------------------------------
__global__ __launch_bounds__(256) void wvec_kernel(
    const float* __restrict__ wmem, const ushort* __restrict__ mem_n,
    ushort* __restrict__ wvec)
{
    __shared__ ushort memL[NM][1032];
    __shared__ float wL[NH][NM];
    const int bs = blockIdx.x;
    const int tid = threadIdx.x;

    for (int t = tid; t < NM * 256; t += 256) {
        int m = t >> 8, c4 = (t & 255) << 2;
        *(ushort4*)&memL[m][c4] = *(const ushort4*)(mem_n + ((size_t)bs * NM + m) * 1024 + c4);
    }
    if (tid < NH * NM) {
        int h = tid / NM, m = tid % NM;
        wL[h][m] = wmem[((size_t)bs * NH + h) * 16 + m];
    }
    __syncthreads();

    for (int h = 0; h < NH; h++) {
#pragma unroll
        for (int c0 = 0; c0 < 1024; c0 += 256) {
            int c = c0 + tid;
            float acc = 0.f;
#pragma unroll
            for (int m = 0; m < NM; m++)
                acc = fmaf(wL[h][m], bf2f(memL[m][c]), acc);
            wvec[((size_t)bs * NH + h) * 1024 + c] = f2bf(acc);
        }
    }
}

// ---------------------------------------------------------------------------
// vproj: mem_ctx[bs,h,d] = wvec[bs,h,:]·Wv[h*64+d,:] + wsum*bv[h*64+d];
// merged[bs, h*64+d] += mem_ctx. Per-head GEMM M=2048,N=64,K=1024.
// ---------------------------------------------------------------------------
__global__ __launch_bounds__(256) void vproj_kernel(
    const ushort* __restrict__ wvec, const float* __restrict__ Wv,
    const float* __restrict__ bv, const float* __restrict__ wmem,
    float* __restrict__ merged)
{
    __shared__ float As[BKK][BM + 1];
    __shared__ float Bs[BKK][BN + 1];
    __shared__ float wsumL[64];
    const int tid = threadIdx.x;
    const int tx = tid & 15, ty = tid >> 4;
    const int row0 = blockIdx.y * BM;
    const int h = blockIdx.z;
    const int lr = tid >> 2;
    const int lc = (tid & 3) << 2;

    if (tid < 64)
        wsumL[tid] = wmem[((size_t)(row0 + tid) * NH + h) * 16 + 12];

    float acc[4][4] = {};
    for (int k0 = 0; k0 < DIM; k0 += BKK) {
        float av[4], bvv[4];
        ld4(wvec + ((size_t)(row0 + lr) * NH + h) * DIM + k0 + lc, av);
        ld4(Wv + (size_t)(h * HD + lr) * DIM + k0 + lc, bvv);
#pragma unroll
        for (int i = 0; i < 4; i++) { As[lc + i][lr] = av[i]; Bs[lc + i][lr] = bvv[i]; }
        __syncthreads();
#pragma unroll
        for (int kk = 0; kk < BKK; kk++) {
            float a[4], b2[4];
#pragma unroll
            for (int i = 0; i < 4; i++) a[i] = As[kk][ty * 4 + i];
#pragma unroll
            for (int j = 0; j < 4; j++) b2[j] = Bs[kk][tx * 4 + j];
#pragma unroll
            for (int i = 0; i < 4; i++)
#pragma unroll
                for (int j = 0; j < 4; j++)
                    acc[i][j] = fmaf(a[i], b2[j], acc[i][j]);
        }
        __syncthreads();
    }
#pragma unroll
    for (int i = 0; i < 4; i++) {
        int r = row0 + ty * 4 + i;
        float ws = wsumL[ty * 4 + i];
#pragma unroll
        for (int j = 0; j < 4; j++) {
            int c = tx * 4 + j;             // 0..63
            merged[(size_t)r * DIM + h * HD + c] += acc[i][j] + ws * bv[h * HD + c];
        }
    }
}

// ---------------------------------------------------------------------------
extern "C" void kernel_launch(void* const* d_in, const int* in_sizes, int n_in,
                              void* d_out, int out_size, void* d_ws, size_t ws_size,
                              hipStream_t stream) {
    const float* x    = (const float*)d_in[0];
    const float* pk   = (const float*)d_in[1];
    const float* pv   = (const float*)d_in[2];
    const float* pq   = (const float*)d_in[3];
    const float* Wqkv = (const float*)d_in[4];
    const float* bqkv = (const float*)d_in[5];
    const float* Wout = (const float*)d_in[6];
    const float* bout = (const float*)d_in[7];
    float* out = (float*)d_out;

    // ws layout: mem_n bf16 50.3MB | qproj/wvec bf16 67.1MB (aliased) |
    //            msc fp32 1.6MB | wmem fp32 2.1MB | merged fp32 8.4MB  (~130MB)
    ushort* mem_n  = (ushort*)d_ws;                        // 24576*1024
    ushort* qproj  = mem_n + (size_t)MEMROWS * 1024;       // 2048*16*1024
    ushort* wvec   = qproj;                                // alias (qproj dead after msc)
    float*  msc    = (float*)(qproj + (size_t)NTOK * NH * 1024);
    float*  wmem   = msc  + (size_t)NTOK * NH * NM;
    float*  merged = wmem + (size_t)NTOK * NH * 16;

    // 1. q,k,v = x @ Wqkv^T + bqkv -> d_out regions (fp32)
    gemm_qkv_kernel<<<dim3(3072 / BN, NTOK / BM), 256, 0, stream>>>(x, Wqkv, bqkv, out);
    // 2. layernorm of mem rows -> bf16
    ln_mem_kernel<<<MEMROWS, 256, 0, stream>>>(pq, pk, pv, mem_n);
    // 3. qproj = q @ Wk_h (batched per head)
    qproj_kernel<<<dim3(DIM / BN, NTOK / BM, NH), 256, 0, stream>>>(
        out, Wqkv + (size_t)DIM * DIM, qproj);
    // 4. mem scores
    mem_scores_kernel<<<NTOK, 256, 0, stream>>>(mem_n, qproj, out, bqkv, msc);
    // 5. attention (token part + softmax) -> merged, wmem
    attn_kernel<<<BATCH * NH * SEQ, 256, 0, stream>>>(out, msc, merged, wmem);
    // 6. wvec = sum_m wmem * mem_n
    wvec_kernel<<<NTOK, 256, 0, stream>>>(wmem, mem_n, wvec);
    // 7. vproj: merged += wvec @ Wv_h^T + wsum*bv
    vproj_kernel<<<dim3(1, NTOK / BM, NH), 256, 0, stream>>>(
        wvec, Wqkv + (size_t)2 * DIM * DIM, bqkv + 2 * DIM, wmem, merged);
    // 8. out = merged @ Wout^T + bout
    gemm_bt<float, float><<<dim3(DIM / BN, NTOK / BM), 256, 0, stream>>>(
        merged, Wout, bout, out, DIM, DIM);
}

// Round 5
// 872.561 us; speedup vs baseline: 3.8571x; 1.9617x over previous
//
#include <hip/hip_runtime.h>

// Problem constants (B=2, S=1024, D=1024, H=16, hd=64, L=4, M=12)
// External tensors fp32. Workspace intermediates bf16/fp32.
#define BATCH 2
#define SEQ   1024
#define DIM   1024
#define NH    16
#define HD    64
#define NL    4
#define NM    12   // 3*NL
#define NTOK  (BATCH*SEQ)          // 2048
#define MEMROWS (BATCH*SEQ*NM)     // 24576
#define OUTT  2097152              // elements per output tensor
#define NEGBIG (-1.0e30f)

typedef __attribute__((ext_vector_type(8))) short short8;   // 8 bf16 (4 VGPRs)
typedef __attribute__((ext_vector_type(4))) float f32x4;    // MFMA C/D

__device__ __forceinline__ float bf2f(ushort u) {
    union { unsigned int i; float f; } t; t.i = ((unsigned int)u) << 16; return t.f;
}
__device__ __forceinline__ ushort f2bf(float f) {
    union { float f; unsigned int i; } t; t.f = f;
    unsigned int i = t.i;
    unsigned int lsb = (i >> 16) & 1u;
    i += 0x7fffu + lsb;
    return (ushort)(i >> 16);
}
__device__ __forceinline__ void ld4(const float* p, float* o) {
    float4 v = *(const float4*)p; o[0] = v.x; o[1] = v.y; o[2] = v.z; o[3] = v.w;
}
__device__ __forceinline__ void ld4(const ushort* p, float* o) {
    ushort4 v = *(const ushort4*)p;
    o[0] = bf2f(v.x); o[1] = bf2f(v.y); o[2] = bf2f(v.z); o[3] = bf2f(v.w);
}
__device__ __forceinline__ void st1(float* p, float v)  { *p = v; }
__device__ __forceinline__ void st1(ushort* p, float v) { *p = f2bf(v); }

#define BM 64
#define BN 64
#define BKK 16

// ---------------------------------------------------------------------------
// Generic GEMM: C[M,N] = A[M,K] @ W[N,K]^T + bias[N], fp32 accumulate.
// ---------------------------------------------------------------------------
template <typename TA, typename TC>
__global__ __launch_bounds__(256) void gemm_bt(
    const TA* __restrict__ A, const float* __restrict__ W,
    const float* __restrict__ bias, TC* __restrict__ C,
    int N, int K)
{
    __shared__ float As[BKK][BM + 1];
    __shared__ float Bs[BKK][BN + 1];
    const int tid = threadIdx.x;
    const int tx = tid & 15, ty = tid >> 4;
    const int row0 = blockIdx.y * BM;
    const int col0 = blockIdx.x * BN;
    const int lr = tid >> 2;
    const int lc = (tid & 3) << 2;

    float acc[4][4] = {};
    for (int k0 = 0; k0 < K; k0 += BKK) {
        float av[4], bv[4];
        ld4(A + (size_t)(row0 + lr) * K + k0 + lc, av);
        ld4(W + (size_t)(col0 + lr) * K + k0 + lc, bv);
#pragma unroll
        for (int i = 0; i < 4; i++) { As[lc + i][lr] = av[i]; Bs[lc + i][lr] = bv[i]; }
        __syncthreads();
#pragma unroll
        for (int kk = 0; kk < BKK; kk++) {
            float a[4], b[4];
#pragma unroll
            for (int i = 0; i < 4; i++) a[i] = As[kk][ty * 4 + i];
#pragma unroll
            for (int j = 0; j < 4; j++) b[j] = Bs[kk][tx * 4 + j];
#pragma unroll
            for (int i = 0; i < 4; i++)
#pragma unroll
                for (int j = 0; j < 4; j++)
                    acc[i][j] = fmaf(a[i], b[j], acc[i][j]);
        }
        __syncthreads();
    }
#pragma unroll
    for (int i = 0; i < 4; i++) {
        int r = row0 + ty * 4 + i;
#pragma unroll
        for (int j = 0; j < 4; j++) {
            int c = col0 + tx * 4 + j;
            st1(C + (size_t)r * N + c, acc[i][j] + bias[c]);
        }
    }
}

// ---------------------------------------------------------------------------
// QKV GEMM, scattered epilogue: fp32 q/k/v into d_out regions AND a bf16 copy
// into ws (qkvb, same (B,H,S,hd) layout, order q|k|v).
// ---------------------------------------------------------------------------
__global__ __launch_bounds__(256) void gemm_qkv_kernel(
    const float* __restrict__ A, const float* __restrict__ W,
    const float* __restrict__ bias, float* __restrict__ out,
    ushort* __restrict__ qkvb)
{
    __shared__ float As[BKK][BM + 1];
    __shared__ float Bs[BKK][BN + 1];
    const int tid = threadIdx.x;
    const int tx = tid & 15, ty = tid >> 4;
    const int row0 = blockIdx.y * BM;
    const int col0 = blockIdx.x * BN;
    const int lr = tid >> 2;
    const int lc = (tid & 3) << 2;

    float acc[4][4] = {};
    for (int k0 = 0; k0 < DIM; k0 += BKK) {
        float av[4], bv[4];
        ld4(A + (size_t)(row0 + lr) * DIM + k0 + lc, av);
        ld4(W + (size_t)(col0 + lr) * DIM + k0 + lc, bv);
#pragma unroll
        for (int i = 0; i < 4; i++) { As[lc + i][lr] = av[i]; Bs[lc + i][lr] = bv[i]; }
        __syncthreads();
#pragma unroll
        for (int kk = 0; kk < BKK; kk++) {
            float a[4], b[4];
#pragma unroll
            for (int i = 0; i < 4; i++) a[i] = As[kk][ty * 4 + i];
#pragma unroll
            for (int j = 0; j < 4; j++) b[j] = Bs[kk][tx * 4 + j];
#pragma unroll
            for (int i = 0; i < 4; i++)
#pragma unroll
                for (int j = 0; j < 4; j++)
                    acc[i][j] = fmaf(a[i], b[j], acc[i][j]);
        }
        __syncthreads();
    }
#pragma unroll
    for (int i = 0; i < 4; i++) {
        int r = row0 + ty * 4 + i;
        int b = r >> 10, s = r & (SEQ - 1);
#pragma unroll
        for (int j = 0; j < 4; j++) {
            int c = col0 + tx * 4 + j;
            int t = c >> 10;                // 0=q,1=k,2=v
            int h = (c >> 6) & 15;
            int d = c & 63;
            float val = acc[i][j] + bias[c];
            size_t idx = (((size_t)(b * NH + h) * SEQ + s) * HD) + d;
            size_t base = (t == 0) ? (size_t)(3 * OUTT)
                        : (t == 1) ? (size_t)(OUTT) : (size_t)(2 * OUTT);
            out[base + idx] = val;
            qkvb[(size_t)t * OUTT + idx] = f2bf(val);
        }
    }
}

// ---------------------------------------------------------------------------
// LayerNorm of mem rows (fp32 in, bf16 out)
// ---------------------------------------------------------------------------
__global__ __launch_bounds__(256) void ln_mem_kernel(
    const float* __restrict__ pq, const float* __restrict__ pk,
    const float* __restrict__ pv, ushort* __restrict__ mem_n)
{
    const int r = blockIdx.x;
    const int idx = r % NM;
    const int bs = r / NM;
    const int s = bs & (SEQ - 1);
    const int b = bs >> 10;
    const int c = idx >> 2;
    const int l = idx & 3;
    const float* src = (c == 0) ? pq : ((c == 1) ? pk : pv);
    const int tid = threadIdx.x;

    float vals[4];
    float sum = 0.f, sumsq = 0.f;
#pragma unroll
    for (int i = 0; i < 4; i++) {
        int dp = i * 256 + tid;
        int h = dp >> 6, d = dp & 63;
        float v = src[((((size_t)(l * BATCH + b) * NH + h) * SEQ + s) * HD) + d];
        vals[i] = v; sum += v; sumsq += v * v;
    }
    __shared__ float rs[256], rq[256];
    rs[tid] = sum; rq[tid] = sumsq;
    __syncthreads();
    for (int st = 128; st > 0; st >>= 1) {
        if (tid < st) { rs[tid] += rs[tid + st]; rq[tid] += rq[tid + st]; }
        __syncthreads();
    }
    float mu  = rs[0] * (1.f / 1024.f);
    float var = fmaxf(rq[0] * (1.f / 1024.f) - mu * mu, 0.f);
    float inv = rsqrtf(var + 1e-5f);
    ushort* dst = mem_n + (size_t)r * 1024;
#pragma unroll
    for (int i = 0; i < 4; i++) {
        int dp = i * 256 + tid;
        dst[dp] = f2bf((vals[i] - mu) * inv);
    }
}

// ---------------------------------------------------------------------------
// qproj[b,s,h,:] = q[b,h,s,:] @ Wk_h  (per-head GEMM: M=2048, N=1024, K=64)
// ---------------------------------------------------------------------------
__global__ __launch_bounds__(256) void qproj_kernel(
    const float* __restrict__ out_qkv, const float* __restrict__ Wk,
    ushort* __restrict__ qproj)
{
    __shared__ float As[BKK][BM + 1];
    __shared__ float Bs[BKK][BN + 1];
    const int tid = threadIdx.x;
    const int tx = tid & 15, ty = tid >> 4;
    const int row0 = blockIdx.y * BM;
    const int col0 = blockIdx.x * BN;
    const int h = blockIdx.z;
    const int lr = tid >> 2;
    const int lc = (tid & 3) << 2;
    const int bkk = tid >> 4;
    const int bc4 = (tid & 15) << 2;

    const float* qbase = out_qkv + (size_t)3 * OUTT;

    float acc[4][4] = {};
    for (int k0 = 0; k0 < HD; k0 += BKK) {
        int row = row0 + lr;
        int b = row >> 10, s = row & (SEQ - 1);
        float av[4], bv[4];
        ld4(qbase + (((size_t)(b * NH + h) * SEQ + s) * HD) + k0 + lc, av);
        ld4(Wk + (size_t)(h * HD + k0 + bkk) * DIM + col0 + bc4, bv);
#pragma unroll
        for (int i = 0; i < 4; i++) As[lc + i][lr] = av[i];
#pragma unroll
        for (int i = 0; i < 4; i++) Bs[bkk][bc4 + i] = bv[i];
        __syncthreads();
#pragma unroll
        for (int kk = 0; kk < BKK; kk++) {
            float a[4], b2[4];
#pragma unroll
            for (int i = 0; i < 4; i++) a[i] = As[kk][ty * 4 + i];
#pragma unroll
            for (int j = 0; j < 4; j++) b2[j] = Bs[kk][tx * 4 + j];
#pragma unroll
            for (int i = 0; i < 4; i++)
#pragma unroll
                for (int j = 0; j < 4; j++)
                    acc[i][j] = fmaf(a[i], b2[j], acc[i][j]);
        }
        __syncthreads();
    }
#pragma unroll
    for (int i = 0; i < 4; i++) {
        int r = row0 + ty * 4 + i;
#pragma unroll
        for (int j = 0; j < 4; j++) {
            int c = col0 + tx * 4 + j;
            qproj[((size_t)r * NH + h) * DIM + c] = f2bf(acc[i][j]);
        }
    }
}

// ---------------------------------------------------------------------------
// mem_scores[(bs*16+h)*12+m] = 0.125*( mem_n[bs,m,:]·qproj[bs,h,:] + q_h·bk_h )
// ---------------------------------------------------------------------------
__global__ __launch_bounds__(256) void mem_scores_kernel(
    const ushort* __restrict__ mem_n, const ushort* __restrict__ qproj,
    const float* __restrict__ out_qkv, const float* __restrict__ bqkv,
    float* __restrict__ msc)
{
    __shared__ ushort memL[NM][1032];
    __shared__ ushort qpL[NH][1032];
    __shared__ float qbPart[NH][4];
    const int bs = blockIdx.x;
    const int tid = threadIdx.x;

    for (int t = tid; t < NM * 256; t += 256) {
        int m = t >> 8, c4 = (t & 255) << 2;
        *(ushort4*)&memL[m][c4] = *(const ushort4*)(mem_n + ((size_t)bs * NM + m) * 1024 + c4);
    }
    for (int t = tid; t < NH * 256; t += 256) {
        int h = t >> 8, c4 = (t & 255) << 2;
        *(ushort4*)&qpL[h][c4] = *(const ushort4*)(qproj + ((size_t)bs * NH + h) * 1024 + c4);
    }
    if (tid >= 192) {
        int t2 = tid - 192;
        int h = t2 >> 2, ch = t2 & 3;
        int b = bs >> 10, s = bs & (SEQ - 1);
        const float* qrow = out_qkv + (size_t)3 * OUTT + ((size_t)(b * NH + h) * SEQ + s) * HD;
        float qb = 0.f;
#pragma unroll
        for (int d = 0; d < 16; d++)
            qb += qrow[ch * 16 + d] * bqkv[DIM + h * HD + ch * 16 + d];
        qbPart[h][ch] = qb;
    }
    __syncthreads();

    if (tid < 192) {
        int h = tid / NM, m = tid % NM;
        float acc = 0.f;
#pragma unroll 4
        for (int c = 0; c < 1024; c++)
            acc = fmaf(bf2f(memL[m][c]), bf2f(qpL[h][c]), acc);
        float qbk = qbPart[h][0] + qbPart[h][1] + qbPart[h][2] + qbPart[h][3];
        msc[((size_t)bs * NH + h) * NM + m] = 0.125f * (acc + qbk);
    }
}

// ---------------------------------------------------------------------------
// Flash attention (MFMA bf16). Block = (qt, bh): 64 q-rows, 4 waves x 16 rows.
// K-tiles of 64. Online softmax in registers (quad shfl_xor butterflies).
// Epilogue folds the 12 mem scores, writes merged (token ctx, fully
// normalized) and wmem (normalized mem weights + their sum at idx 12).
// Fragment layouts per verified guide facts:
//   C/D: col=lane&15, row=(lane>>4)*4+reg   [m89/m91]
//   A:   m=lane&15,  k=(lane>>4)*8+j        [m118/m120]
//   B (rows x K form): n=lane&15, k=(lane>>4)*8+j   [m97 gemm_bt ladder]
// ---------------------------------------------------------------------------
#define TQ 64
#define TK 64
__global__ __launch_bounds__(256) void flash_attn_kernel(
    const ushort* __restrict__ qkvb, const float* __restrict__ msc,
    float* __restrict__ merged, float* __restrict__ wmem)
{
    __shared__ ushort Ks[TK][72];      // K-tile, [key][dim], rows 144B (16B-aligned)
    __shared__ ushort Vt[HD][72];      // V-tile transposed, [dim][key]
    __shared__ ushort Ps[4][16][72];   // per-wave P round-trip, [qrow][key]

    const int bxr = blockIdx.x;                       // 0..15
    const int qt = (bxr & 1) ? (bxr >> 1) : (15 - (bxr >> 1));  // balance causal work
    const int bh = blockIdx.y;                        // 0..31
    const int b = bh >> 4, h = bh & 15;
    const int tid = threadIdx.x;
    const int w = tid >> 6;                           // wave 0..3
    const int lane = tid & 63;
    const int n = lane & 15;                          // frag n/m index
    const int qd = lane >> 4;                         // quad 0..3

    const ushort* qb = qkvb;                          // (B,H,S,hd)
    const ushort* kb = qkvb + (size_t)OUTT;
    const ushort* vb = qkvb + (size_t)2 * OUTT;
    const size_t headoff = (size_t)bh * SEQ * HD;

    // Q fragments in registers for the whole kernel
    const int qrow0 = qt * TQ + w * 16;
    const ushort* qp = qb + headoff + (size_t)(qrow0 + n) * HD;
    short8 qf0 = *(const short8*)(qp + qd * 8);
    short8 qf1 = *(const short8*)(qp + 32 + qd * 8);

    float mrow[4], lrow[4];
    f32x4 Oacc[4];
#pragma unroll
    for (int r = 0; r < 4; r++) { mrow[r] = NEGBIG; lrow[r] = 0.f; }
#pragma unroll
    for (int nt = 0; nt < 4; nt++) Oacc[nt] = (f32x4){0.f, 0.f, 0.f, 0.f};

    for (int kt = 0; kt <= qt; kt++) {
        // ---- stage K tile ([key][dim]) and V tile transposed ([dim][key]) ----
        {
            int key = tid >> 2;
            int c0 = (tid & 3) * 16;
            const ushort* kg = kb + headoff + (size_t)(kt * TK + key) * HD + c0;
            *(short8*)&Ks[key][c0]     = *(const short8*)kg;
            *(short8*)&Ks[key][c0 + 8] = *(const short8*)(kg + 8);
            const ushort* vg = vb + headoff + (size_t)(kt * TK + key) * HD + c0;
            ushort vs[16];
            *(short8*)&vs[0] = *(const short8*)vg;
            *(short8*)&vs[8] = *(const short8*)(vg + 8);
#pragma unroll
            for (int i = 0; i < 16; i++) Vt[c0 + i][key] = vs[i];
        }
        __syncthreads();

        // ---- S = Q K^T (16 rows x 64 keys per wave) ----
        f32x4 sacc[4];
#pragma unroll
        for (int kc = 0; kc < 4; kc++) {
            short8 kf0 = *(const short8*)&Ks[kc * 16 + n][qd * 8];
            short8 kf1 = *(const short8*)&Ks[kc * 16 + n][32 + qd * 8];
            f32x4 z = (f32x4){0.f, 0.f, 0.f, 0.f};
            z = __builtin_amdgcn_mfma_f32_16x16x32_bf16(qf0, kf0, z, 0, 0, 0);
            z = __builtin_amdgcn_mfma_f32_16x16x32_bf16(qf1, kf1, z, 0, 0, 0);
            sacc[kc] = z;
        }
        // scale + causal mask (only the diagonal tile can mask)
        const bool diag = (kt == qt);
#pragma unroll
        for (int kc = 0; kc < 4; kc++) {
#pragma unroll
            for (int r = 0; r < 4; r++) {
                float sv = sacc[kc][r] * 0.125f;
                if (diag) {
                    int qrow = qrow0 + qd * 4 + r;
                    int key = kt * TK + kc * 16 + n;
                    if (key > qrow) sv = NEGBIG;
                }
                sacc[kc][r] = sv;
            }
        }
        // ---- online softmax (row stats via quad butterflies) ----
        float alpha[4];
#pragma unroll
        for (int r = 0; r < 4; r++) {
            float mx = fmaxf(fmaxf(sacc[0][r], sacc[1][r]), fmaxf(sacc[2][r], sacc[3][r]));
            mx = fmaxf(mx, __shfl_xor(mx, 1));
            mx = fmaxf(mx, __shfl_xor(mx, 2));
            mx = fmaxf(mx, __shfl_xor(mx, 4));
            mx = fmaxf(mx, __shfl_xor(mx, 8));
            float mnew = fmaxf(mrow[r], mx);
            alpha[r] = __expf(mrow[r] - mnew);
            mrow[r] = mnew;
        }
        float psum[4] = {0.f, 0.f, 0.f, 0.f};
#pragma unroll
        for (int kc = 0; kc < 4; kc++) {
#pragma unroll
            for (int r = 0; r < 4; r++) {
                float p = __expf(sacc[kc][r] - mrow[r]);
                psum[r] += p;
                Ps[w][qd * 4 + r][kc * 16 + n] = f2bf(p);
            }
        }
#pragma unroll
        for (int r = 0; r < 4; r++) {
            float ps = psum[r];
            ps += __shfl_xor(ps, 1);
            ps += __shfl_xor(ps, 2);
            ps += __shfl_xor(ps, 4);
            ps += __shfl_xor(ps, 8);
            lrow[r] = alpha[r] * lrow[r] + ps;
        }
        // rescale O by alpha (C-layout: reg r <-> row qd*4+r)
#pragma unroll
        for (int nt = 0; nt < 4; nt++)
#pragma unroll
            for (int r = 0; r < 4; r++)
                Oacc[nt][r] *= alpha[r];
        // ---- O += P V ----
        short8 pf0 = *(const short8*)&Ps[w][n][qd * 8];
        short8 pf1 = *(const short8*)&Ps[w][n][32 + qd * 8];
#pragma unroll
        for (int nt = 0; nt < 4; nt++) {
            short8 vf0 = *(const short8*)&Vt[nt * 16 + n][qd * 8];
            short8 vf1 = *(const short8*)&Vt[nt * 16 + n][32 + qd * 8];
            f32x4 z = Oacc[nt];
            z = __builtin_amdgcn_mfma_f32_16x16x32_bf16(pf0, vf0, z, 0, 0, 0);
            z = __builtin_amdgcn_mfma_f32_16x16x32_bf16(pf1, vf1, z, 0, 0, 0);
            Oacc[nt] = z;
        }
        __syncthreads();
    }

    // ---- epilogue: fold mem scores, write merged + wmem ----
#pragma unroll
    for (int r = 0; r < 4; r++) {
        int srow = qrow0 + qd * 4 + r;
        const float* mp = msc + ((size_t)(b * SEQ + srow) * NH + h) * NM;
        float mm = NEGBIG;
#pragma unroll
        for (int j = 0; j < NM; j++) mm = fmaxf(mm, mp[j]);
        float mf = fmaxf(mrow[r], mm);
        float al = __expf(mrow[r] - mf);
        float msum = 0.f;
#pragma unroll
        for (int j = 0; j < NM; j++) msum += __expf(mp[j] - mf);
        float lf = al * lrow[r] + msum;
        float inv = 1.f / lf;
        float scale = al * inv;
        float* mrow_out = merged + (size_t)(b * SEQ + srow) * DIM + h * HD;
#pragma unroll
        for (int nt = 0; nt < 4; nt++)
            mrow_out[nt * 16 + n] = Oacc[nt][r] * scale;
        size_t wb = ((size_t)(b * SEQ + srow) * NH + h) * 16;
        if (n < 12)       wmem[wb + n]  = __expf(mp[n] - mf) * inv;
        else if (n == 12) wmem[wb + 12] = msum * inv;
    }
}

// ---------------------------------------------------------------------------
// wvec[bs,h,:] = sum_m wmem[bs,h,m] * mem_n[bs,m,:]  (bf16 out)
// ---------------------------------------------------------------------------
__global__ __launch_bounds__(256) void wvec_kernel(
    const float* __restrict__ wmem, const ushort* __restrict__ mem_n,
    ushort* __restrict__ wvec)
{
    __shared__ ushort memL[NM][1032];
    __shared__ float wL[NH][NM];
    const int bs = blockIdx.x;
    const int tid = threadIdx.x;

    for (int t = tid; t < NM * 256; t += 256) {
        int m = t >> 8, c4 = (t & 255) << 2;
        *(ushort4*)&memL[m][c4] = *(const ushort4*)(mem_n + ((size_t)bs * NM + m) * 1024 + c4);
    }
    if (tid < NH * NM) {
        int h = tid / NM, m = tid % NM;
        wL[h][m] = wmem[((size_t)bs * NH + h) * 16 + m];
    }
    __syncthreads();

    for (int h = 0; h < NH; h++) {
#pragma unroll
        for (int c0 = 0; c0 < 1024; c0 += 256) {
            int c = c0 + tid;
            float acc = 0.f;
#pragma unroll
            for (int m = 0; m < NM; m++)
                acc = fmaf(wL[h][m], bf2f(memL[m][c]), acc);
            wvec[((size_t)bs * NH + h) * 1024 + c] = f2bf(acc);
        }
    }
}

// ---------------------------------------------------------------------------
// vproj: merged[bs, h*64+d] += wvec[bs,h,:]·Wv[h*64+d,:] + wsum*bv[h*64+d]
// ---------------------------------------------------------------------------
__global__ __launch_bounds__(256) void vproj_kernel(
    const ushort* __restrict__ wvec, const float* __restrict__ Wv,
    const float* __restrict__ bv, const float* __restrict__ wmem,
    float* __restrict__ merged)
{
    __shared__ float As[BKK][BM + 1];
    __shared__ float Bs[BKK][BN + 1];
    __shared__ float wsumL[64];
    const int tid = threadIdx.x;
    const int tx = tid & 15, ty = tid >> 4;
    const int row0 = blockIdx.y * BM;
    const int h = blockIdx.z;
    const int lr = tid >> 2;
    const int lc = (tid & 3) << 2;

    if (tid < 64)
        wsumL[tid] = wmem[((size_t)(row0 + tid) * NH + h) * 16 + 12];

    float acc[4][4] = {};
    for (int k0 = 0; k0 < DIM; k0 += BKK) {
        float av[4], bvv[4];
        ld4(wvec + ((size_t)(row0 + lr) * NH + h) * DIM + k0 + lc, av);
        ld4(Wv + (size_t)(h * HD + lr) * DIM + k0 + lc, bvv);
#pragma unroll
        for (int i = 0; i < 4; i++) { As[lc + i][lr] = av[i]; Bs[lc + i][lr] = bvv[i]; }
        __syncthreads();
#pragma unroll
        for (int kk = 0; kk < BKK; kk++) {
            float a[4], b2[4];
#pragma unroll
            for (int i = 0; i < 4; i++) a[i] = As[kk][ty * 4 + i];
#pragma unroll
            for (int j = 0; j < 4; j++) b2[j] = Bs[kk][tx * 4 + j];
#pragma unroll
            for (int i = 0; i < 4; i++)
#pragma unroll
                for (int j = 0; j < 4; j++)
                    acc[i][j] = fmaf(a[i], b2[j], acc[i][j]);
        }
        __syncthreads();
    }
#pragma unroll
    for (int i = 0; i < 4; i++) {
        int r = row0 + ty * 4 + i;
        float ws = wsumL[ty * 4 + i];
#pragma unroll
        for (int j = 0; j < 4; j++) {
            int c = tx * 4 + j;
            merged[(size_t)r * DIM + h * HD + c] += acc[i][j] + ws * bv[h * HD + c];
        }
    }
}

// ---------------------------------------------------------------------------
extern "C" void kernel_launch(void* const* d_in, const int* in_sizes, int n_in,
                              void* d_out, int out_size, void* d_ws, size_t ws_size,
                              hipStream_t stream) {
    const float* x    = (const float*)d_in[0];
    const float* pk   = (const float*)d_in[1];
    const float* pv   = (const float*)d_in[2];
    const float* pq   = (const float*)d_in[3];
    const float* Wqkv = (const float*)d_in[4];
    const float* bqkv = (const float*)d_in[5];
    const float* Wout = (const float*)d_in[6];
    const float* bout = (const float*)d_in[7];
    float* out = (float*)d_out;

    // ws layout: mem_n bf16 50.3MB | qproj/wvec bf16 67.1MB (aliased) |
    // msc fp32 1.6MB | wmem fp32 2.1MB | merged fp32 8.4MB | qkvb bf16 12.6MB
    ushort* mem_n  = (ushort*)d_ws;                        // 24576*1024
    ushort* qproj  = mem_n + (size_t)MEMROWS * 1024;       // 2048*16*1024
    ushort* wvec   = qproj;                                // alias (qproj dead after msc)
    float*  msc    = (float*)(qproj + (size_t)NTOK * NH * 1024);
    float*  wmem   = msc  + (size_t)NTOK * NH * NM;
    float*  merged = wmem + (size_t)NTOK * NH * 16;
    ushort* qkvb   = (ushort*)(merged + (size_t)NTOK * DIM);   // 3*OUTT bf16

    // 1. q,k,v = x @ Wqkv^T + bqkv -> d_out (fp32) + qkvb (bf16)
    gemm_qkv_kernel<<<dim3(3072 / BN, NTOK / BM), 256, 0, stream>>>(x, Wqkv, bqkv, out, qkvb);
    // 2. layernorm of mem rows -> bf16
    ln_mem_kernel<<<MEMROWS, 256, 0, stream>>>(pq, pk, pv, mem_n);
    // 3. qproj = q @ Wk_h (batched per head)
    qproj_kernel<<<dim3(DIM / BN, NTOK / BM, NH), 256, 0, stream>>>(
        out, Wqkv + (size_t)DIM * DIM, qproj);
    // 4. mem scores
    mem_scores_kernel<<<NTOK, 256, 0, stream>>>(mem_n, qproj, out, bqkv, msc);
    // 5. flash attention (MFMA) -> merged, wmem
    flash_attn_kernel<<<dim3(16, 32), 256, 0, stream>>>(qkvb, msc, merged, wmem);
    // 6. wvec = sum_m wmem * mem_n
    wvec_kernel<<<NTOK, 256, 0, stream>>>(wmem, mem_n, wvec);
    // 7. vproj: merged += wvec @ Wv_h^T + wsum*bv
    vproj_kernel<<<dim3(1, NTOK / BM, NH), 256, 0, stream>>>(
        wvec, Wqkv + (size_t)2 * DIM * DIM, bqkv + 2 * DIM, wmem, merged);
    // 8. out = merged @ Wout^T + bout
    gemm_bt<float, float><<<dim3(DIM / BN, NTOK / BM), 256, 0, stream>>>(
        merged, Wout, bout, out, DIM, DIM);
}

// Round 6
// 368.021 us; speedup vs baseline: 9.1451x; 2.3710x over previous
//
#include <hip/hip_runtime.h>

// Problem constants (B=2, S=1024, D=1024, H=16, hd=64, L=4, M=12)
#define BATCH 2
#define SEQ   1024
#define DIM   1024
#define NH    16
#define HD    64
#define NM    12
#define NTOK  (BATCH*SEQ)          // 2048
#define MEMROWS (BATCH*SEQ*NM)     // 24576
#define OUTT  2097152              // elements per output tensor
#define NEGBIG (-1.0e30f)

typedef __attribute__((ext_vector_type(8))) short short8;   // 8 bf16 (4 VGPRs)
typedef __attribute__((ext_vector_type(4))) float f32x4;    // MFMA C/D

__device__ __forceinline__ float bf2f(ushort u) {
    union { unsigned int i; float f; } t; t.i = ((unsigned int)u) << 16; return t.f;
}
__device__ __forceinline__ ushort f2bf(float f) {
    union { float f; unsigned int i; } t; t.f = f;
    unsigned int i = t.i;
    unsigned int lsb = (i >> 16) & 1u;
    i += 0x7fffu + lsb;
    return (ushort)(i >> 16);
}

// ---------------------------------------------------------------------------
// fp32 -> bf16 conversion for x, Wqkv, Wout (one pass, float4-vectorized)
// ---------------------------------------------------------------------------
__global__ __launch_bounds__(256) void cvt3_kernel(
    const float* __restrict__ a, ushort* __restrict__ ab, int na4,
    const float* __restrict__ b, ushort* __restrict__ bb, int nb4,
    const float* __restrict__ c, ushort* __restrict__ cb, int nc4)
{
    int i = blockIdx.x * 256 + threadIdx.x;
    if (i >= na4 + nb4 + nc4) return;
    const float* src; ushort* dst; int j;
    if (i < na4)            { src = a; dst = ab; j = i; }
    else if (i < na4 + nb4) { src = b; dst = bb; j = i - na4; }
    else                    { src = c; dst = cb; j = i - na4 - nb4; }
    float4 v = ((const float4*)src)[j];
    ushort4 o; o.x = f2bf(v.x); o.y = f2bf(v.y); o.z = f2bf(v.z); o.w = f2bf(v.w);
    ((ushort4*)dst)[j] = o;
}

// ---------------------------------------------------------------------------
// MFMA GEMM core conventions (verified in flash kernel / m89-m120 facts):
//  A-frag: m=lane&15, k=qd*8+j ; B-frag: n=lane&15, k=qd*8+j
//  C/D:    col=lane&15, row=qd*4+reg
// LDS tiles padded to 40 elems/row (80 B, 16B-aligned).
// ---------------------------------------------------------------------------

// qkv GEMM: [2048x1024]x[3072x1024]^T + bias -> fp32 k,v,q in d_out + bf16 qkvb
__global__ __launch_bounds__(256) void mfma_qkv_kernel(
    const ushort* __restrict__ xb, const ushort* __restrict__ Wb,
    const float* __restrict__ bias, float* __restrict__ out,
    ushort* __restrict__ qkvb)
{
    __shared__ ushort As[128][40];
    __shared__ ushort Bs[128][40];
    const int tid = threadIdx.x;
    const int w = tid >> 6, lane = tid & 63;
    const int n = lane & 15, qd = lane >> 4;
    const int wr = (w >> 1) * 64, wc = (w & 1) * 64;
    const int row0 = blockIdx.y * 128, col0 = blockIdx.x * 128;
    const int r1 = tid >> 2, o1 = (tid & 3) * 8;
    const int r2 = (tid + 256) >> 2, o2 = ((tid + 256) & 3) * 8;

    f32x4 acc[4][4];
#pragma unroll
    for (int mt = 0; mt < 4; mt++)
#pragma unroll
        for (int nt = 0; nt < 4; nt++) acc[mt][nt] = (f32x4){0.f, 0.f, 0.f, 0.f};

    for (int k0 = 0; k0 < 1024; k0 += 32) {
        *(short8*)&As[r1][o1] = *(const short8*)(xb + (size_t)(row0 + r1) * 1024 + k0 + o1);
        *(short8*)&As[r2][o2] = *(const short8*)(xb + (size_t)(row0 + r2) * 1024 + k0 + o2);
        *(short8*)&Bs[r1][o1] = *(const short8*)(Wb + (size_t)(col0 + r1) * 1024 + k0 + o1);
        *(short8*)&Bs[r2][o2] = *(const short8*)(Wb + (size_t)(col0 + r2) * 1024 + k0 + o2);
        __syncthreads();
        short8 af[4], bf[4];
#pragma unroll
        for (int mt = 0; mt < 4; mt++) af[mt] = *(const short8*)&As[wr + mt * 16 + n][qd * 8];
#pragma unroll
        for (int nt = 0; nt < 4; nt++) bf[nt] = *(const short8*)&Bs[wc + nt * 16 + n][qd * 8];
#pragma unroll
        for (int mt = 0; mt < 4; mt++)
#pragma unroll
            for (int nt = 0; nt < 4; nt++)
                acc[mt][nt] = __builtin_amdgcn_mfma_f32_16x16x32_bf16(af[mt], bf[nt], acc[mt][nt], 0, 0, 0);
        __syncthreads();
    }
#pragma unroll
    for (int mt = 0; mt < 4; mt++)
#pragma unroll
        for (int nt = 0; nt < 4; nt++)
#pragma unroll
            for (int r = 0; r < 4; r++) {
                int row = row0 + wr + mt * 16 + qd * 4 + r;
                int col = col0 + wc + nt * 16 + n;
                float val = acc[mt][nt][r] + bias[col];
                int t = col >> 10, h = (col >> 6) & 15, d = col & 63;
                int b = row >> 10, s = row & 1023;
                size_t idx = (((size_t)(b * NH + h) * SEQ + s) * HD) + d;
                size_t base = (t == 0) ? (size_t)3 * OUTT : (t == 1) ? (size_t)OUTT : (size_t)2 * OUTT;
                out[base + idx] = val;
                qkvb[(size_t)t * OUTT + idx] = f2bf(val);
            }
}

// out GEMM: mergedb[2048x1024] x Woutb[1024x1024]^T + bout -> d_out fp32
__global__ __launch_bounds__(256) void mfma_out_kernel(
    const ushort* __restrict__ Ab, const ushort* __restrict__ Wb,
    const float* __restrict__ bias, float* __restrict__ C)
{
    __shared__ ushort As[128][40];
    __shared__ ushort Bs[128][40];
    const int tid = threadIdx.x;
    const int w = tid >> 6, lane = tid & 63;
    const int n = lane & 15, qd = lane >> 4;
    const int wr = (w >> 1) * 64, wc = (w & 1) * 64;
    const int row0 = blockIdx.y * 128, col0 = blockIdx.x * 128;
    const int r1 = tid >> 2, o1 = (tid & 3) * 8;
    const int r2 = (tid + 256) >> 2, o2 = ((tid + 256) & 3) * 8;

    f32x4 acc[4][4];
#pragma unroll
    for (int mt = 0; mt < 4; mt++)
#pragma unroll
        for (int nt = 0; nt < 4; nt++) acc[mt][nt] = (f32x4){0.f, 0.f, 0.f, 0.f};

    for (int k0 = 0; k0 < 1024; k0 += 32) {
        *(short8*)&As[r1][o1] = *(const short8*)(Ab + (size_t)(row0 + r1) * 1024 + k0 + o1);
        *(short8*)&As[r2][o2] = *(const short8*)(Ab + (size_t)(row0 + r2) * 1024 + k0 + o2);
        *(short8*)&Bs[r1][o1] = *(const short8*)(Wb + (size_t)(col0 + r1) * 1024 + k0 + o1);
        *(short8*)&Bs[r2][o2] = *(const short8*)(Wb + (size_t)(col0 + r2) * 1024 + k0 + o2);
        __syncthreads();
        short8 af[4], bf[4];
#pragma unroll
        for (int mt = 0; mt < 4; mt++) af[mt] = *(const short8*)&As[wr + mt * 16 + n][qd * 8];
#pragma unroll
        for (int nt = 0; nt < 4; nt++) bf[nt] = *(const short8*)&Bs[wc + nt * 16 + n][qd * 8];
#pragma unroll
        for (int mt = 0; mt < 4; mt++)
#pragma unroll
            for (int nt = 0; nt < 4; nt++)
                acc[mt][nt] = __builtin_amdgcn_mfma_f32_16x16x32_bf16(af[mt], bf[nt], acc[mt][nt], 0, 0, 0);
        __syncthreads();
    }
#pragma unroll
    for (int mt = 0; mt < 4; mt++)
#pragma unroll
        for (int nt = 0; nt < 4; nt++)
#pragma unroll
            for (int r = 0; r < 4; r++) {
                int row = row0 + wr + mt * 16 + qd * 4 + r;
                int col = col0 + wc + nt * 16 + n;
                C[(size_t)row * 1024 + col] = acc[mt][nt][r] + bias[col];
            }
}

// qproj per head: q_h[2048x64] @ WkBlock_h[64x1024] -> qproj bf16 (B transposed on stage)
__global__ __launch_bounds__(256) void mfma_qproj_kernel(
    const ushort* __restrict__ qkvb, const ushort* __restrict__ Wkb,
    ushort* __restrict__ qproj)
{
    __shared__ ushort As[128][40];
    __shared__ ushort Bs[128][40];
    const int tid = threadIdx.x;
    const int w = tid >> 6, lane = tid & 63;
    const int n = lane & 15, qd = lane >> 4;
    const int wr = (w >> 1) * 64, wc = (w & 1) * 64;
    const int row0 = blockIdx.y * 128, col0 = blockIdx.x * 128;
    const int h = blockIdx.z;
    const int b = row0 >> 10, s0 = row0 & 1023;
    const ushort* Abase = qkvb + ((size_t)(b * NH + h) * SEQ + s0) * HD;
    const int r1 = tid >> 2, o1 = (tid & 3) * 8;
    const int r2 = (tid + 256) >> 2, o2 = ((tid + 256) & 3) * 8;
    const int bkk = tid >> 3, bc0 = (tid & 7) * 16;

    f32x4 acc[4][4];
#pragma unroll
    for (int mt = 0; mt < 4; mt++)
#pragma unroll
        for (int nt = 0; nt < 4; nt++) acc[mt][nt] = (f32x4){0.f, 0.f, 0.f, 0.f};

    for (int k0 = 0; k0 < 64; k0 += 32) {
        *(short8*)&As[r1][o1] = *(const short8*)(Abase + (size_t)r1 * HD + k0 + o1);
        *(short8*)&As[r2][o2] = *(const short8*)(Abase + (size_t)r2 * HD + k0 + o2);
        // B transpose stage: Bs[c][kk] = Wk[h*64+k0+kk][col0+c]
        {
            const ushort* bsrc = Wkb + (size_t)(h * HD + k0 + bkk) * 1024 + col0 + bc0;
            ushort tmp[16];
            *(short8*)&tmp[0] = *(const short8*)bsrc;
            *(short8*)&tmp[8] = *(const short8*)(bsrc + 8);
#pragma unroll
            for (int i = 0; i < 16; i++) Bs[bc0 + i][bkk] = tmp[i];
        }
        __syncthreads();
        short8 af[4], bf[4];
#pragma unroll
        for (int mt = 0; mt < 4; mt++) af[mt] = *(const short8*)&As[wr + mt * 16 + n][qd * 8];
#pragma unroll
        for (int nt = 0; nt < 4; nt++) bf[nt] = *(const short8*)&Bs[wc + nt * 16 + n][qd * 8];
#pragma unroll
        for (int mt = 0; mt < 4; mt++)
#pragma unroll
            for (int nt = 0; nt < 4; nt++)
                acc[mt][nt] = __builtin_amdgcn_mfma_f32_16x16x32_bf16(af[mt], bf[nt], acc[mt][nt], 0, 0, 0);
        __syncthreads();
    }
#pragma unroll
    for (int mt = 0; mt < 4; mt++)
#pragma unroll
        for (int nt = 0; nt < 4; nt++)
#pragma unroll
            for (int r = 0; r < 4; r++) {
                int token = row0 + wr + mt * 16 + qd * 4 + r;
                int col = col0 + wc + nt * 16 + n;
                qproj[((size_t)token * NH + h) * 1024 + col] = f2bf(acc[mt][nt][r]);
            }
}

// vproj per head: merged[t, h*64+d] += wvec_h[t,:]·Wv[h*64+d,:] + wsum*bv (in-place bf16)
__global__ __launch_bounds__(256) void mfma_vproj_kernel(
    const ushort* __restrict__ wvecb, const ushort* __restrict__ Wvb,
    const float* __restrict__ bv, const float* __restrict__ wmem,
    ushort* __restrict__ mergedb)
{
    __shared__ ushort As[128][40];
    __shared__ ushort Bs[64][40];
    const int tid = threadIdx.x;
    const int w = tid >> 6, lane = tid & 63;
    const int n = lane & 15, qd = lane >> 4;
    const int wr = (w >> 1) * 64, wc = (w & 1) * 32;
    const int row0 = blockIdx.x * 128;
    const int h = blockIdx.y;
    const int r1 = tid >> 2, o1 = (tid & 3) * 8;
    const int r2 = (tid + 256) >> 2, o2 = ((tid + 256) & 3) * 8;

    f32x4 acc[4][2];
#pragma unroll
    for (int mt = 0; mt < 4; mt++)
#pragma unroll
        for (int nt = 0; nt < 2; nt++) acc[mt][nt] = (f32x4){0.f, 0.f, 0.f, 0.f};

    for (int k0 = 0; k0 < 1024; k0 += 32) {
        *(short8*)&As[r1][o1] = *(const short8*)(wvecb + ((size_t)(row0 + r1) * NH + h) * 1024 + k0 + o1);
        *(short8*)&As[r2][o2] = *(const short8*)(wvecb + ((size_t)(row0 + r2) * NH + h) * 1024 + k0 + o2);
        *(short8*)&Bs[r1 & 63][o1] = *(const short8*)(Wvb + (size_t)(h * HD + (r1 & 63)) * 1024 + k0 + o1);
        __syncthreads();
        short8 af[4], bf[2];
#pragma unroll
        for (int mt = 0; mt < 4; mt++) af[mt] = *(const short8*)&As[wr + mt * 16 + n][qd * 8];
#pragma unroll
        for (int nt = 0; nt < 2; nt++) bf[nt] = *(const short8*)&Bs[wc + nt * 16 + n][qd * 8];
#pragma unroll
        for (int mt = 0; mt < 4; mt++)
#pragma unroll
            for (int nt = 0; nt < 2; nt++)
                acc[mt][nt] = __builtin_amdgcn_mfma_f32_16x16x32_bf16(af[mt], bf[nt], acc[mt][nt], 0, 0, 0);
        __syncthreads();
    }
#pragma unroll
    for (int mt = 0; mt < 4; mt++)
#pragma unroll
        for (int nt = 0; nt < 2; nt++)
#pragma unroll
            for (int r = 0; r < 4; r++) {
                int token = row0 + wr + mt * 16 + qd * 4 + r;
                int d = wc + nt * 16 + n;
                float ws = wmem[((size_t)token * NH + h) * 16 + 12];
                size_t mi = (size_t)token * DIM + h * HD + d;
                float val = bf2f(mergedb[mi]) + acc[mt][nt][r] + ws * bv[h * HD + d];
                mergedb[mi] = f2bf(val);
            }
}

// mem_scores fused: per token, D[h][m] = qproj_h · mem_m via one MFMA chain.
__global__ __launch_bounds__(256) void msc_fused_kernel(
    const ushort* __restrict__ qproj, const ushort* __restrict__ mem_n,
    const ushort* __restrict__ qkvb, const float* __restrict__ bqkv,
    float* __restrict__ msc)
{
    const int tid = threadIdx.x;
    const int w = tid >> 6, lane = tid & 63;
    const int n = lane & 15, qd = lane >> 4;
    const int bs = blockIdx.x * 4 + w;

    float qbk = 0.f;
    if (lane < 16) {
        int b = bs >> 10, s = bs & 1023;
        const ushort* qrow = qkvb + ((size_t)(b * NH + lane) * SEQ + s) * HD;
        const float* bk = bqkv + DIM + lane * HD;
#pragma unroll
        for (int d = 0; d < HD; d++) qbk += bf2f(qrow[d]) * bk[d];
    }
    f32x4 acc = (f32x4){0.f, 0.f, 0.f, 0.f};
    const ushort* qpB = qproj + ((size_t)bs * NH + n) * 1024;
    const int mrow = (n < NM) ? n : 0;
    const ushort* mmB = mem_n + ((size_t)bs * NM + mrow) * 1024;
    for (int k0 = 0; k0 < 1024; k0 += 32) {
        short8 af = *(const short8*)(qpB + k0 + qd * 8);
        short8 bf = *(const short8*)(mmB + k0 + qd * 8);
        acc = __builtin_amdgcn_mfma_f32_16x16x32_bf16(af, bf, acc, 0, 0, 0);
    }
#pragma unroll
    for (int r = 0; r < 4; r++) {
        int h = qd * 4 + r;
        float qb = __shfl(qbk, h);
        if (n < NM)
            msc[((size_t)bs * NH + h) * NM + n] = 0.125f * (acc[r] + qb);
    }
}

// ---------------------------------------------------------------------------
// LayerNorm of mem rows (fp32 in, bf16 out)
// ---------------------------------------------------------------------------
__global__ __launch_bounds__(256) void ln_mem_kernel(
    const float* __restrict__ pq, const float* __restrict__ pk,
    const float* __restrict__ pv, ushort* __restrict__ mem_n)
{
    const int r = blockIdx.x;
    const int idx = r % NM;
    const int bs = r / NM;
    const int s = bs & (SEQ - 1);
    const int b = bs >> 10;
    const int c = idx >> 2;
    const int l = idx & 3;
    const float* src = (c == 0) ? pq : ((c == 1) ? pk : pv);
    const int tid = threadIdx.x;

    float vals[4];
    float sum = 0.f, sumsq = 0.f;
#pragma unroll
    for (int i = 0; i < 4; i++) {
        int dp = i * 256 + tid;
        int h = dp >> 6, d = dp & 63;
        float v = src[((((size_t)(l * BATCH + b) * NH + h) * SEQ + s) * HD) + d];
        vals[i] = v; sum += v; sumsq += v * v;
    }
    __shared__ float rs[256], rq[256];
    rs[tid] = sum; rq[tid] = sumsq;
    __syncthreads();
    for (int st = 128; st > 0; st >>= 1) {
        if (tid < st) { rs[tid] += rs[tid + st]; rq[tid] += rq[tid + st]; }
        __syncthreads();
    }
    float mu  = rs[0] * (1.f / 1024.f);
    float var = fmaxf(rq[0] * (1.f / 1024.f) - mu * mu, 0.f);
    float inv = rsqrtf(var + 1e-5f);
    ushort* dst = mem_n + (size_t)r * 1024;
#pragma unroll
    for (int i = 0; i < 4; i++) {
        int dp = i * 256 + tid;
        dst[dp] = f2bf((vals[i] - mu) * inv);
    }
}

// ---------------------------------------------------------------------------
// Flash attention (MFMA bf16), unchanged structure; merged now bf16.
// ---------------------------------------------------------------------------
#define TQ 64
#define TK 64
__global__ __launch_bounds__(256) void flash_attn_kernel(
    const ushort* __restrict__ qkvb, const float* __restrict__ msc,
    ushort* __restrict__ mergedb, float* __restrict__ wmem)
{
    __shared__ ushort Ks[TK][72];
    __shared__ ushort Vt[HD][72];
    __shared__ ushort Ps[4][16][72];

    const int bxr = blockIdx.x;
    const int qt = (bxr & 1) ? (bxr >> 1) : (15 - (bxr >> 1));
    const int bh = blockIdx.y;
    const int b = bh >> 4, h = bh & 15;
    const int tid = threadIdx.x;
    const int w = tid >> 6;
    const int lane = tid & 63;
    const int n = lane & 15;
    const int qd = lane >> 4;

    const ushort* qb = qkvb;
    const ushort* kb = qkvb + (size_t)OUTT;
    const ushort* vb = qkvb + (size_t)2 * OUTT;
    const size_t headoff = (size_t)bh * SEQ * HD;

    const int qrow0 = qt * TQ + w * 16;
    const ushort* qp = qb + headoff + (size_t)(qrow0 + n) * HD;
    short8 qf0 = *(const short8*)(qp + qd * 8);
    short8 qf1 = *(const short8*)(qp + 32 + qd * 8);

    float mrow[4], lrow[4];
    f32x4 Oacc[4];
#pragma unroll
    for (int r = 0; r < 4; r++) { mrow[r] = NEGBIG; lrow[r] = 0.f; }
#pragma unroll
    for (int nt = 0; nt < 4; nt++) Oacc[nt] = (f32x4){0.f, 0.f, 0.f, 0.f};

    for (int kt = 0; kt <= qt; kt++) {
        {
            int key = tid >> 2;
            int c0 = (tid & 3) * 16;
            const ushort* kg = kb + headoff + (size_t)(kt * TK + key) * HD + c0;
            *(short8*)&Ks[key][c0]     = *(const short8*)kg;
            *(short8*)&Ks[key][c0 + 8] = *(const short8*)(kg + 8);
            const ushort* vg = vb + headoff + (size_t)(kt * TK + key) * HD + c0;
            ushort vs[16];
            *(short8*)&vs[0] = *(const short8*)vg;
            *(short8*)&vs[8] = *(const short8*)(vg + 8);
#pragma unroll
            for (int i = 0; i < 16; i++) Vt[c0 + i][key] = vs[i];
        }
        __syncthreads();

        f32x4 sacc[4];
#pragma unroll
        for (int kc = 0; kc < 4; kc++) {
            short8 kf0 = *(const short8*)&Ks[kc * 16 + n][qd * 8];
            short8 kf1 = *(const short8*)&Ks[kc * 16 + n][32 + qd * 8];
            f32x4 z = (f32x4){0.f, 0.f, 0.f, 0.f};
            z = __builtin_amdgcn_mfma_f32_16x16x32_bf16(qf0, kf0, z, 0, 0, 0);
            z = __builtin_amdgcn_mfma_f32_16x16x32_bf16(qf1, kf1, z, 0, 0, 0);
            sacc[kc] = z;
        }
        const bool diag = (kt == qt);
#pragma unroll
        for (int kc = 0; kc < 4; kc++) {
#pragma unroll
            for (int r = 0; r < 4; r++) {
                float sv = sacc[kc][r] * 0.125f;
                if (diag) {
                    int qrow = qrow0 + qd * 4 + r;
                    int key = kt * TK + kc * 16 + n;
                    if (key > qrow) sv = NEGBIG;
                }
                sacc[kc][r] = sv;
            }
        }
        float alpha[4];
#pragma unroll
        for (int r = 0; r < 4; r++) {
            float mx = fmaxf(fmaxf(sacc[0][r], sacc[1][r]), fmaxf(sacc[2][r], sacc[3][r]));
            mx = fmaxf(mx, __shfl_xor(mx, 1));
            mx = fmaxf(mx, __shfl_xor(mx, 2));
            mx = fmaxf(mx, __shfl_xor(mx, 4));
            mx = fmaxf(mx, __shfl_xor(mx, 8));
            float mnew = fmaxf(mrow[r], mx);
            alpha[r] = __expf(mrow[r] - mnew);
            mrow[r] = mnew;
        }
        float psum[4] = {0.f, 0.f, 0.f, 0.f};
#pragma unroll
        for (int kc = 0; kc < 4; kc++) {
#pragma unroll
            for (int r = 0; r < 4; r++) {
                float p = __expf(sacc[kc][r] - mrow[r]);
                psum[r] += p;
                Ps[w][qd * 4 + r][kc * 16 + n] = f2bf(p);
            }
        }
#pragma unroll
        for (int r = 0; r < 4; r++) {
            float ps = psum[r];
            ps += __shfl_xor(ps, 1);
            ps += __shfl_xor(ps, 2);
            ps += __shfl_xor(ps, 4);
            ps += __shfl_xor(ps, 8);
            lrow[r] = alpha[r] * lrow[r] + ps;
        }
#pragma unroll
        for (int nt = 0; nt < 4; nt++)
#pragma unroll
            for (int r = 0; r < 4; r++)
                Oacc[nt][r] *= alpha[r];
        short8 pf0 = *(const short8*)&Ps[w][n][qd * 8];
        short8 pf1 = *(const short8*)&Ps[w][n][32 + qd * 8];
#pragma unroll
        for (int nt = 0; nt < 4; nt++) {
            short8 vf0 = *(const short8*)&Vt[nt * 16 + n][qd * 8];
            short8 vf1 = *(const short8*)&Vt[nt * 16 + n][32 + qd * 8];
            f32x4 z = Oacc[nt];
            z = __builtin_amdgcn_mfma_f32_16x16x32_bf16(pf0, vf0, z, 0, 0, 0);
            z = __builtin_amdgcn_mfma_f32_16x16x32_bf16(pf1, vf1, z, 0, 0, 0);
            Oacc[nt] = z;
        }
        __syncthreads();
    }

#pragma unroll
    for (int r = 0; r < 4; r++) {
        int srow = qrow0 + qd * 4 + r;
        const float* mp = msc + ((size_t)(b * SEQ + srow) * NH + h) * NM;
        float mm = NEGBIG;
#pragma unroll
        for (int j = 0; j < NM; j++) mm = fmaxf(mm, mp[j]);
        float mf = fmaxf(mrow[r], mm);
        float al = __expf(mrow[r] - mf);
        float msum = 0.f;
#pragma unroll
        for (int j = 0; j < NM; j++) msum += __expf(mp[j] - mf);
        float lf = al * lrow[r] + msum;
        float inv = 1.f / lf;
        float scale = al * inv;
        ushort* mrow_out = mergedb + (size_t)(b * SEQ + srow) * DIM + h * HD;
#pragma unroll
        for (int nt = 0; nt < 4; nt++)
            mrow_out[nt * 16 + n] = f2bf(Oacc[nt][r] * scale);
        size_t wb = ((size_t)(b * SEQ + srow) * NH + h) * 16;
        if (n < 12)       wmem[wb + n]  = __expf(mp[n] - mf) * inv;
        else if (n == 12) wmem[wb + 12] = msum * inv;
    }
}

// ---------------------------------------------------------------------------
// wvec[bs,h,:] = sum_m wmem[bs,h,m] * mem_n[bs,m,:]  (bf16 out)
// ---------------------------------------------------------------------------
__global__ __launch_bounds__(256) void wvec_kernel(
    const float* __restrict__ wmem, const ushort* __restrict__ mem_n,
    ushort* __restrict__ wvecb)
{
    __shared__ ushort memL[NM][1032];
    __shared__ float wL[NH][NM];
    const int bs = blockIdx.x;
    const int tid = threadIdx.x;

    for (int t = tid; t < NM * 256; t += 256) {
        int m = t >> 8, c4 = (t & 255) << 2;
        *(ushort4*)&memL[m][c4] = *(const ushort4*)(mem_n + ((size_t)bs * NM + m) * 1024 + c4);
    }
    if (tid < NH * NM) {
        int h = tid / NM, m = tid % NM;
        wL[h][m] = wmem[((size_t)bs * NH + h) * 16 + m];
    }
    __syncthreads();

    for (int h = 0; h < NH; h++) {
#pragma unroll
        for (int c0 = 0; c0 < 1024; c0 += 256) {
            int c = c0 + tid;
            float acc = 0.f;
#pragma unroll
            for (int m = 0; m < NM; m++)
                acc = fmaf(wL[h][m], bf2f(memL[m][c]), acc);
            wvecb[((size_t)bs * NH + h) * 1024 + c] = f2bf(acc);
        }
    }
}

// ---------------------------------------------------------------------------
extern "C" void kernel_launch(void* const* d_in, const int* in_sizes, int n_in,
                              void* d_out, int out_size, void* d_ws, size_t ws_size,
                              hipStream_t stream) {
    const float* x    = (const float*)d_in[0];
    const float* pk   = (const float*)d_in[1];
    const float* pv   = (const float*)d_in[2];
    const float* pq   = (const float*)d_in[3];
    const float* Wqkv = (const float*)d_in[4];
    const float* bqkv = (const float*)d_in[5];
    const float* Wout = (const float*)d_in[6];
    const float* bout = (const float*)d_in[7];
    float* out = (float*)d_out;

    // ws: mem_n 50.3 | qproj/wvecb 67.1 (aliased) | msc 1.6 | wmem 2.1 |
    //     qkvb 12.6 | Wqkvb 6.3 | Woutb 2.1 | xb/mergedb 4.2 (aliased) ~146 MB
    ushort* mem_n  = (ushort*)d_ws;
    ushort* qproj  = mem_n + (size_t)MEMROWS * 1024;
    ushort* wvecb  = qproj;                                 // alias: qproj dead after msc
    float*  msc    = (float*)(qproj + (size_t)NTOK * NH * 1024);
    float*  wmem   = msc + (size_t)NTOK * NH * NM;
    ushort* qkvb   = (ushort*)(wmem + (size_t)NTOK * NH * 16);
    ushort* Wqkvb  = qkvb + (size_t)3 * OUTT;
    ushort* Woutb  = Wqkvb + (size_t)3072 * 1024;
    ushort* xb     = Woutb + (size_t)1024 * 1024;
    ushort* mergedb = xb;                                   // alias: xb dead after qkv gemm

    const int na4 = NTOK * DIM / 4, nb4 = 3 * DIM * DIM / 4, nc4 = DIM * DIM / 4;

    // 1. bf16 conversions
    cvt3_kernel<<<(na4 + nb4 + nc4 + 255) / 256, 256, 0, stream>>>(
        x, xb, na4, Wqkv, Wqkvb, nb4, Wout, Woutb, nc4);
    // 2. qkv GEMM (MFMA) -> d_out fp32 k,v,q + qkvb bf16
    mfma_qkv_kernel<<<dim3(24, 16), 256, 0, stream>>>(xb, Wqkvb, bqkv, out, qkvb);
    // 3. layernorm of mem rows -> bf16
    ln_mem_kernel<<<MEMROWS, 256, 0, stream>>>(pq, pk, pv, mem_n);
    // 4. qproj (MFMA, per head)
    mfma_qproj_kernel<<<dim3(8, 16, NH), 256, 0, stream>>>(
        qkvb, Wqkvb + (size_t)DIM * DIM, qproj);
    // 5. mem scores (fused MFMA per token)
    msc_fused_kernel<<<NTOK / 4, 256, 0, stream>>>(qproj, mem_n, qkvb, bqkv, msc);
    // 6. flash attention -> mergedb bf16, wmem
    flash_attn_kernel<<<dim3(16, 32), 256, 0, stream>>>(qkvb, msc, mergedb, wmem);
    // 7. wvec
    wvec_kernel<<<NTOK, 256, 0, stream>>>(wmem, mem_n, wvecb);
    // 8. vproj (MFMA, per head): mergedb += wvec@Wv^T + wsum*bv (in place)
    mfma_vproj_kernel<<<dim3(16, NH), 256, 0, stream>>>(
        wvecb, Wqkvb + (size_t)2 * DIM * DIM, bqkv + 2 * DIM, wmem, mergedb);
    // 9. out GEMM (MFMA) -> d_out fp32
    mfma_out_kernel<<<dim3(8, 16), 256, 0, stream>>>(mergedb, Woutb, bout, out);
}